// Round 15
// baseline (2546.528 us; speedup 1.0000x reference)
//
#include <hip/hip_runtime.h>
#include <stdint.h>

#define T_STEPS 1024
#define BATCH   512
#define INF     64
#define HID     128
#define OUTF    2

typedef float f32x4 __attribute__((ext_vector_type(4)));

// d_out[0..1023] = z_sum [512][2], d_out[1024] = spikerate.
__global__ void zero_kernel(unsigned int* __restrict__ counter)
{
    *counter = 0u;
}

#define BARRIER() asm volatile("s_waitcnt lgkmcnt(0)\n\ts_barrier" ::: "memory")

// asm-volatile loads: results CANNOT be rematerialized -> weights stay in VGPRs.
#define GLD0(d,p)  asm volatile("global_load_dwordx4 %0, %1, off"            : "=v"(d) : "v"(p) : "memory")
#define GLD(d,p,o) asm volatile("global_load_dwordx4 %0, %1, off offset:" #o : "=v"(d) : "v"(p) : "memory")
#define VMWAIT()   asm volatile("s_waitcnt vmcnt(0)" ::: "memory")
#define LOAD8(p) \
    GLD0(w0,(p)); GLD(w1,(p),16); GLD(w2,(p),32); GLD(w3,(p),48); \
    GLD(w4,(p),64); GLD(w5,(p),80); GLD(w6,(p),96); GLD(w7,(p),112); VMWAIT()

#define CH(q) { float4 i4 = ir[q]; \
    acc = fmaf(i4.x, w##q.x, acc); acc = fmaf(i4.y, w##q.y, acc); \
    acc = fmaf(i4.z, w##q.z, acc); acc = fmaf(i4.w, w##q.w, acc); }
#define CH8 CH(0)CH(1)CH(2)CH(3)CH(4)CH(5)CH(6)CH(7)

// grid 512 x 896 threads (14 waves); block = ONE batch row b. ~74KB LDS -> 2 blocks/CU.
// 8-stage software pipeline, one lgkm-barrier per step. At iteration i:
//   W1a (tid 512..639): r1(i+6)  = chain(x(i+6)[0..31])        -> r1[par]
//   W1b (640..767):     inp(i+5) = chain(r1, x(i+5)[32..63])   -> inp[slot]
//   W2a (0..127):       p1(i+4)  = chain(inp[0..31])           -> p1[par]
//   W2b (128..255):     p2(i+3)  = chain(p1, inp[32..63])      -> p2[par]
//   W2c (256..383):     p3(i+2)  = chain(p2, inp[64..95])      -> p3[par]
//   W2d (384..511):     pre(i+1) = chain(p3, inp[96..127])     -> pre[par]
//   R   (768..831):     step i: 16-deep rec scan + LIF + ballots (masks in-wave)
//   X   (832..895):     x(i+7) -> x ring; prefetch x(i+9)
// Each role holds exactly 8 float4 weights (asm-pinned). Bit-exact semantics
// (absmax==0.0 rounds 8-14): f64 state/elementwise in np op order (contract off);
// inp/pre f32 seq-k single-acc FMA chains (K-split passes exact f32 partials);
// rec = exact f64 sum (order-free).
__global__ __launch_bounds__(896, 7)
void snn_seq(const float* __restrict__ x,        // [T][B][64]
             const float* __restrict__ W_in,     // [128][64]
             const float* __restrict__ cWi,      // [128][128]
             const float* __restrict__ Wrec,     // [128][128]
             const float* __restrict__ W_out,    // [2][128]
             const float* __restrict__ b_out,    // [2]
             const float* __restrict__ v_th,     // [128]
             const float* __restrict__ v_leak1,  // [1]
             const float* __restrict__ v_reset,  // [128]
             const float* __restrict__ tau_mem,  // [128]
             const float* __restrict__ tau_syn,  // [128]
             float* __restrict__ out,            // [512][2] + [1]
             unsigned int* __restrict__ counter)
{
    #pragma clang fp contract(off)

    extern __shared__ char smem[];
    float* Wrec_T  = (float*)smem;             // [128][128]: Wrec_T[j][h] = Wrec[h][j]
    float* inp_lds = Wrec_T + HID * HID;       // [8 slot][128]
    float* x_lds   = inp_lds + 8 * HID;        // [4 slot][64]
    float* p1_lds  = x_lds + 4 * INF;          // [2][128]
    float* p2_lds  = p1_lds + 2 * HID;         // [2][128]
    float* p3_lds  = p2_lds + 2 * HID;         // [2][128]
    float* r1_lds  = p3_lds + 2 * HID;         // [2][128]
    float* pre_lds = r1_lds + 2 * HID;         // [2][128]

    const int tid = threadIdx.x;
    const int b   = blockIdx.x;

    // ---- stage Wrec transposed (all threads)
    for (int idx = tid; idx < HID * HID; idx += 896)
        Wrec_T[idx] = Wrec[(idx & (HID - 1)) * HID + (idx >> 7)];

    if (tid < 512) {
        // ============ W2a..d: pre-chain quarters of cWi ============
        const int h    = tid & (HID - 1);
        const int st   = tid >> 7;            // 0..3
        const int koff = st * 32;
        f32x4 w0, w1, w2, w3, w4, w5, w6, w7;
        LOAD8(cWi + h * HID + koff);
        float* inP  = (st == 1) ? p1_lds : (st == 2) ? p2_lds : p3_lds;  // unused for st==0
        float* outP = (st == 0) ? p1_lds : (st == 1) ? p2_lds
                    : (st == 2) ? p3_lds : pre_lds;
        const int toff = 4 - st;              // W2a:+4 .. W2d:+1
        BARRIER();
        for (int i = -6; i < T_STEPS; ++i) {
            const int t = i + toff;
            if (t >= 0 && t < T_STEPS) {
                const float4* ir = (const float4*)(inp_lds + (t & 7) * HID + koff);
                float acc = (st == 0) ? 0.f : inP[(t & 1) * HID + h];
                CH8
                outP[(t & 1) * HID + h] = acc;
            }
            BARRIER();
        }
    } else if (tid < 768) {
        // ============ W1a,b: inp-chain halves of W_in ============
        const int h    = tid & (HID - 1);
        const int sub  = (tid - 512) >> 7;    // 0: W1a, 1: W1b
        const int koff = sub * 32;
        f32x4 w0, w1, w2, w3, w4, w5, w6, w7;
        LOAD8(W_in + h * INF + koff);
        const int toff = 6 - sub;             // W1a:+6, W1b:+5
        BARRIER();
        for (int i = -6; i < T_STEPS; ++i) {
            const int t = i + toff;
            if (t >= 0 && t < T_STEPS) {
                const float4* ir = (const float4*)(x_lds + (t & 3) * INF + koff);
                float acc = (sub == 0) ? 0.f : r1_lds[(t & 1) * HID + h];
                CH8
                if (sub == 0) r1_lds[(t & 1) * HID + h] = acc;
                else          inp_lds[(t & 7) * HID + h] = acc;
            }
            BARRIER();
        }
    } else if (tid < 832) {
        // ============ R: rec scan + LIF, 2 neurons/lane, masks in-wave ============
        const int l  = tid - 768;
        const int h0 = 2 * l, h1 = 2 * l + 1;

        const double vth0  = (double)v_th[h0],    vth1  = (double)v_th[h1];
        const double vleak = (double)v_leak1[0];
        const double vrs0  = (double)v_reset[h0], vrs1  = (double)v_reset[h1];
        const double dtm0  = 0.001 * (double)tau_mem[h0];
        const double dtm1  = 0.001 * (double)tau_mem[h1];
        const double dts0  = 0.001 * (double)tau_syn[h0];
        const double dts1  = 0.001 * (double)tau_syn[h1];

        double v0 = 0.0, v1 = 0.0, c0 = 0.0, c1 = 0.0;
        int cnt0 = 0, cnt1 = 0;
        unsigned long long me = 0ull, mo = 0ull;   // z(i-1): even/odd neurons

        BARRIER();
        for (int i = -6; i < T_STEPS; ++i) {
            if (i >= 0) {
                float2 pp = *(const float2*)(pre_lds + (i & 1) * HID + h0);  // pre(i)

                // 16-deep batched exact-f64 scan (order-free)
                double q00 = 0.0, q01 = 0.0, q10 = 0.0, q11 = 0.0;
                {
                    unsigned long long A = me, B = mo;
                    while (A | B) {
                        float2 wv0 = make_float2(0.f, 0.f), wv1 = wv0, wv2 = wv0, wv3 = wv0,
                               wv4 = wv0, wv5 = wv0, wv6 = wv0, wv7 = wv0,
                               wv8 = wv0, wv9 = wv0, wva = wv0, wvb = wv0,
                               wvc = wv0, wvd = wv0, wve = wv0, wvf = wv0;
                        if (A) { int j = __builtin_ctzll(A); A &= A - 1; wv0 = *(const float2*)(Wrec_T + (2 * j) * HID + h0); }
                        if (A) { int j = __builtin_ctzll(A); A &= A - 1; wv1 = *(const float2*)(Wrec_T + (2 * j) * HID + h0); }
                        if (A) { int j = __builtin_ctzll(A); A &= A - 1; wv2 = *(const float2*)(Wrec_T + (2 * j) * HID + h0); }
                        if (A) { int j = __builtin_ctzll(A); A &= A - 1; wv3 = *(const float2*)(Wrec_T + (2 * j) * HID + h0); }
                        if (A) { int j = __builtin_ctzll(A); A &= A - 1; wv4 = *(const float2*)(Wrec_T + (2 * j) * HID + h0); }
                        if (A) { int j = __builtin_ctzll(A); A &= A - 1; wv5 = *(const float2*)(Wrec_T + (2 * j) * HID + h0); }
                        if (A) { int j = __builtin_ctzll(A); A &= A - 1; wv6 = *(const float2*)(Wrec_T + (2 * j) * HID + h0); }
                        if (A) { int j = __builtin_ctzll(A); A &= A - 1; wv7 = *(const float2*)(Wrec_T + (2 * j) * HID + h0); }
                        if (B) { int j = __builtin_ctzll(B); B &= B - 1; wv8 = *(const float2*)(Wrec_T + (2 * j + 1) * HID + h0); }
                        if (B) { int j = __builtin_ctzll(B); B &= B - 1; wv9 = *(const float2*)(Wrec_T + (2 * j + 1) * HID + h0); }
                        if (B) { int j = __builtin_ctzll(B); B &= B - 1; wva = *(const float2*)(Wrec_T + (2 * j + 1) * HID + h0); }
                        if (B) { int j = __builtin_ctzll(B); B &= B - 1; wvb = *(const float2*)(Wrec_T + (2 * j + 1) * HID + h0); }
                        if (B) { int j = __builtin_ctzll(B); B &= B - 1; wvc = *(const float2*)(Wrec_T + (2 * j + 1) * HID + h0); }
                        if (B) { int j = __builtin_ctzll(B); B &= B - 1; wvd = *(const float2*)(Wrec_T + (2 * j + 1) * HID + h0); }
                        if (B) { int j = __builtin_ctzll(B); B &= B - 1; wve = *(const float2*)(Wrec_T + (2 * j + 1) * HID + h0); }
                        if (B) { int j = __builtin_ctzll(B); B &= B - 1; wvf = *(const float2*)(Wrec_T + (2 * j + 1) * HID + h0); }
                        q00 += (double)wv0.x; q10 += (double)wv0.y;
                        q01 += (double)wv1.x; q11 += (double)wv1.y;
                        q00 += (double)wv2.x; q10 += (double)wv2.y;
                        q01 += (double)wv3.x; q11 += (double)wv3.y;
                        q00 += (double)wv4.x; q10 += (double)wv4.y;
                        q01 += (double)wv5.x; q11 += (double)wv5.y;
                        q00 += (double)wv6.x; q10 += (double)wv6.y;
                        q01 += (double)wv7.x; q11 += (double)wv7.y;
                        q00 += (double)wv8.x; q10 += (double)wv8.y;
                        q01 += (double)wv9.x; q11 += (double)wv9.y;
                        q00 += (double)wva.x; q10 += (double)wva.y;
                        q01 += (double)wvb.x; q11 += (double)wvb.y;
                        q00 += (double)wvc.x; q10 += (double)wvc.y;
                        q01 += (double)wvd.x; q11 += (double)wvd.y;
                        q00 += (double)wve.x; q10 += (double)wve.y;
                        q01 += (double)wvf.x; q11 += (double)wvf.y;
                    }
                }
                double rec0 = q00 + q01;
                double rec1 = q10 + q11;

                // LIF (float64, np op order, no contraction)
                double vd0 = v0 + dtm0 * ((vleak - v0) + c0);
                double id0 = c0 - dts0 * c0;
                bool   z0  = (vd0 - vth0) > 0.0;
                v0 = z0 ? vrs0 : vd0;
                c0 = (id0 + (double)pp.x) + rec0;
                cnt0 += z0 ? 1 : 0;

                double vd1 = v1 + dtm1 * ((vleak - v1) + c1);
                double id1 = c1 - dts1 * c1;
                bool   z1  = (vd1 - vth1) > 0.0;
                v1 = z1 ? vrs1 : vd1;
                c1 = (id1 + (double)pp.y) + rec1;
                cnt1 += z1 ? 1 : 0;

                me = __ballot(z0);
                mo = __ballot(z1);
            }
            BARRIER();
        }
        pre_lds[h0] = (float)cnt0;   // park counts (<=1024: exact in f32)
        pre_lds[h1] = (float)cnt1;
    } else {
        // ============ X: x prefetch ============
        const int l = tid - 832;
        x_lds[0 * INF + l] = x[(size_t)(0 * BATCH + b) * INF + l];
        x_lds[1 * INF + l] = x[(size_t)(1 * BATCH + b) * INF + l];
        x_lds[2 * INF + l] = x[(size_t)(2 * BATCH + b) * INF + l];
        x_lds[3 * INF + l] = x[(size_t)(3 * BATCH + b) * INF + l];
        float rA = x[(size_t)(4 * BATCH + b) * INF + l];
        float rB = x[(size_t)(5 * BATCH + b) * INF + l];
        BARRIER();
        for (int i = -6; i < T_STEPS; ++i) {
            const int t = i + 7;
            if (t >= 4 && t < T_STEPS) {
                x_lds[(t & 3) * INF + l] = rA;
                rA = rB;
                int tn = (t + 2 < T_STEPS) ? t + 2 : T_STEPS - 1;
                rB = x[((size_t)tn * BATCH + b) * INF + l];
            }
            BARRIER();
        }
    }

    __syncthreads();

    // ---- epilogue: z_sum[b] = (sum_t z)@W_out.T + T*b_out ; global spike count
    const float* cnt_lds = pre_lds;
    if (tid < OUTF) {
        double sAcc = 0.0;
        for (int hh = 0; hh < HID; ++hh)
            sAcc += (double)cnt_lds[hh] * (double)W_out[tid * HID + hh];
        out[(size_t)b * OUTF + tid] = (float)(sAcc + 1024.0 * (double)b_out[tid]);
    }
    if (tid == 0) {
        unsigned int tot = 0;
        for (int k2 = 0; k2 < HID; ++k2) tot += (unsigned int)cnt_lds[k2];
        atomicAdd(counter, tot);
    }
}

__global__ void finalize_kernel(float* __restrict__ out)
{
    unsigned int c = ((const unsigned int*)out)[BATCH * OUTF];
    out[BATCH * OUTF] = (float)c * 0x1p-26f;   // / (1024*512*128), exact pow2
}

extern "C" void kernel_launch(void* const* d_in, const int* in_sizes, int n_in,
                              void* d_out, int out_size, void* d_ws, size_t ws_size,
                              hipStream_t stream) {
    (void)in_sizes; (void)n_in; (void)d_ws; (void)ws_size; (void)out_size;

    const float* x       = (const float*)d_in[0];
    const float* W_in    = (const float*)d_in[1];
    const float* cWi     = (const float*)d_in[2];
    const float* cWr     = (const float*)d_in[3];
    const float* W_out   = (const float*)d_in[4];
    const float* b_out   = (const float*)d_in[5];
    // d_in[6] = alpha (unused in forward)
    const float* v_th    = (const float*)d_in[7];
    const float* v_leak  = (const float*)d_in[8];
    const float* v_reset = (const float*)d_in[9];
    const float* tau_mem = (const float*)d_in[10];
    const float* tau_syn = (const float*)d_in[11];
    float* out = (float*)d_out;
    unsigned int* counter = (unsigned int*)out + BATCH * OUTF;

    zero_kernel<<<1, 1, 0, stream>>>(counter);

    const size_t lds_bytes =
        (size_t)(HID * HID + 8 * HID + 4 * INF + 5 * 2 * HID) * sizeof(float);
    snn_seq<<<dim3(512), dim3(896), lds_bytes, stream>>>(
        x, W_in, cWi, cWr, W_out, b_out, v_th, v_leak, v_reset,
        tau_mem, tau_syn, out, counter);

    finalize_kernel<<<1, 1, 0, stream>>>(out);
}

// Round 16
// 617.610 us; speedup vs baseline: 4.1232x; 4.1232x over previous
//
#include <hip/hip_runtime.h>
#include <stdint.h>

#define T_STEPS 1024
#define BATCH   512
#define INF     64
#define HID     128
#define OUTF    2

// d_out[0..1023] = z_sum [512][2], d_out[1024] = spikerate.
__global__ void zero_kernel(unsigned int* __restrict__ counter)
{
    *counter = 0u;
}

#define FOR16(M) M(0)M(1)M(2)M(3)M(4)M(5)M(6)M(7)M(8)M(9)M(10)M(11)M(12)M(13)M(14)M(15)
#define BARRIER() asm volatile("s_waitcnt lgkmcnt(0)\n\ts_barrier" ::: "memory")

// grid 512 x 512 threads; block = ONE batch row b. 69KB LDS -> 2 blocks/CU.
// launch_bounds(512,2): allocator targets ~4 waves/EU -> ~128 VGPR budget;
// every role needs <= ~95 VGPRs (max 16 float4 weights) -> weights stay resident.
// (Round 9/11/12/14/15 A/B series: allocator targets ~2x the declared min
//  occupancy; min=1 -> 204 VGPR resident, min=2 -> ~128, min=4 -> 44, min=7 -> 36+spill.)
// Roles (wave-aligned), pipeline at step i:
//   tid   0..127 (W2a): q(i+2)   = f32 chain k=0..63   of inp(i+2)      -> q_lds
//   tid 128..255 (W2b): pre(i+1) = f32 chain k=64..127 CONTINUING q(i+1)-> pre_lds
//   tid 256..383 (W1) : inp(i+3) = x(i+3) @ W_in.T (64-chain, 1 out/lane)-> inp_lds
//   tid 384..447 (R)  : step i: rec scan (in-reg masks) + LIF + ballots
//   tid 448..511 (X)  : x prefetch: ds_write x(i+5/i+6), issue load x(i+7/i+8)
// Buffers: inp[4], x[4], q[2], pre[2]; every handoff crosses >=1 barrier.
// Bit-exact semantics (verified absmax==0.0 rounds 8-15):
//   - v,i state + elementwise: float64, np op order, no contraction
//   - inp/pre: f32 seq-k single-accumulator FMA chains (K-split passes the exact
//     f32 partial through LDS -> identical op sequence)
//   - rec: f64 sum of f32 weights — exact in any order
__global__ __launch_bounds__(512, 2)
void snn_seq(const float* __restrict__ x,        // [T][B][64]
             const float* __restrict__ W_in,     // [128][64]
             const float* __restrict__ cWi,      // [128][128]
             const float* __restrict__ Wrec,     // [128][128]
             const float* __restrict__ W_out,    // [2][128]
             const float* __restrict__ b_out,    // [2]
             const float* __restrict__ v_th,     // [128]
             const float* __restrict__ v_leak1,  // [1]
             const float* __restrict__ v_reset,  // [128]
             const float* __restrict__ tau_mem,  // [128]
             const float* __restrict__ tau_syn,  // [128]
             float* __restrict__ out,            // [512][2] + [1]
             unsigned int* __restrict__ counter)
{
    #pragma clang fp contract(off)

    extern __shared__ char smem[];
    float* Wrec_T  = (float*)smem;                 // [128][128]: Wrec_T[j][h] = Wrec[h][j]
    float* inp_lds = Wrec_T + HID * HID;           // [4 slot][128]
    float* x_lds   = inp_lds + 4 * HID;            // [4 slot][64]
    float* q_lds   = x_lds + 4 * INF;              // [2 slot][128]
    float* pre_lds = q_lds + 2 * HID;              // [2 slot][128]

    const int tid = threadIdx.x;
    const int b   = blockIdx.x;

    // ---- stage Wrec transposed (all 512 threads)
    for (int idx = tid; idx < HID * HID; idx += 512)
        Wrec_T[idx] = Wrec[(idx & (HID - 1)) * HID + (idx >> 7)];

    if (tid < 128) {
        // ============ W2a: q = chain(inp[0..63]) with cWi row first half ============
        const int h = tid;
        const float4* cwr = (const float4*)(cWi + h * HID);
        #define DECL_C(q) float4 c##q = cwr[q];
        FOR16(DECL_C)
        #undef DECL_C

        #define S2A(q) { float4 i4 = ir4[q]; \
            acc = fmaf(i4.x, c##q.x, acc); acc = fmaf(i4.y, c##q.y, acc); \
            acc = fmaf(i4.z, c##q.z, acc); acc = fmaf(i4.w, c##q.w, acc); }

        __syncthreads();                       // B0
        BARRIER();                             // B1 (W1 computed inp(0))
        {   // P2: q(0)
            const float4* ir4 = (const float4*)(inp_lds + 0 * HID);
            float acc = 0.f; FOR16(S2A)
            q_lds[0 * HID + h] = acc;
        }
        BARRIER();                             // B2
        {   // P3: q(1)
            const float4* ir4 = (const float4*)(inp_lds + 1 * HID);
            float acc = 0.f; FOR16(S2A)
            q_lds[1 * HID + h] = acc;
        }
        BARRIER();                             // B3
        for (int i = 0; i < T_STEPS; i += 2) {
            {   // even: q(i+2), slot (i+2)&3, qslot (i+2)&1 = 0
                const float4* ir4 = (const float4*)(inp_lds + ((i + 2) & 3) * HID);
                float acc = 0.f; FOR16(S2A)
                q_lds[0 * HID + h] = acc;
            }
            BARRIER();
            {   // odd: q(i+3), slot (i+3)&3, qslot 1
                const float4* ir4 = (const float4*)(inp_lds + ((i + 3) & 3) * HID);
                float acc = 0.f; FOR16(S2A)
                q_lds[1 * HID + h] = acc;
            }
            BARRIER();
        }
        #undef S2A
    } else if (tid < 256) {
        // ============ W2b: pre = chain(q, inp[64..127]) with cWi row second half ============
        const int h = tid - 128;
        const float4* cwr = (const float4*)(cWi + h * HID) + 16;
        #define DECL_D(q) float4 d##q = cwr[q];
        FOR16(DECL_D)
        #undef DECL_D

        #define S2B(q) { float4 i4 = ir4[q]; \
            acc = fmaf(i4.x, d##q.x, acc); acc = fmaf(i4.y, d##q.y, acc); \
            acc = fmaf(i4.z, d##q.z, acc); acc = fmaf(i4.w, d##q.w, acc); }

        __syncthreads();                       // B0
        BARRIER();                             // B1
        BARRIER();                             // B2
        {   // P3: pre(0) from q(0), inp(0)[64..127]
            const float4* ir4 = (const float4*)(inp_lds + 0 * HID) + 16;
            float acc = q_lds[0 * HID + h];
            FOR16(S2B)
            pre_lds[0 * HID + h] = acc;
        }
        BARRIER();                             // B3
        for (int i = 0; i < T_STEPS; i += 2) {
            {   // even: pre(i+1), inp slot (i+1)&3, q/pre slot 1
                const float4* ir4 = (const float4*)(inp_lds + ((i + 1) & 3) * HID) + 16;
                float acc = q_lds[1 * HID + h];
                FOR16(S2B)
                pre_lds[1 * HID + h] = acc;
            }
            BARRIER();
            {   // odd: pre(i+2), inp slot (i+2)&3, q/pre slot 0
                const float4* ir4 = (const float4*)(inp_lds + ((i + 2) & 3) * HID) + 16;
                float acc = q_lds[0 * HID + h];
                FOR16(S2B)
                pre_lds[0 * HID + h] = acc;
            }
            BARRIER();
        }
        #undef S2B
    } else if (tid < 384) {
        // ============ W1: inp = x @ W_in.T, one output/lane ============
        const int l = tid - 256;
        const float4* wra = (const float4*)(W_in + l * INF);
        #define DECL_A(q) float4 a##q = wra[q];
        FOR16(DECL_A)
        #undef DECL_A

        #define S1(q) { float4 x4 = xr4[q]; \
            acc = fmaf(x4.x, a##q.x, acc); acc = fmaf(x4.y, a##q.y, acc); \
            acc = fmaf(x4.z, a##q.z, acc); acc = fmaf(x4.w, a##q.w, acc); }

        __syncthreads();                       // B0 (x(0..3) staged by X)
        {   // P1: inp(0)
            const float4* xr4 = (const float4*)(x_lds + 0 * INF);
            float acc = 0.f; FOR16(S1)
            inp_lds[0 * HID + l] = acc;
        }
        BARRIER();                             // B1
        {   // P2: inp(1)
            const float4* xr4 = (const float4*)(x_lds + 1 * INF);
            float acc = 0.f; FOR16(S1)
            inp_lds[1 * HID + l] = acc;
        }
        BARRIER();                             // B2
        {   // P3: inp(2)
            const float4* xr4 = (const float4*)(x_lds + 2 * INF);
            float acc = 0.f; FOR16(S1)
            inp_lds[2 * HID + l] = acc;
        }
        BARRIER();                             // B3
        for (int i = 0; i < T_STEPS; i += 2) {
            {   // even: inp(i+3), x/inp slot (i+3)&3
                const int s = (i + 3) & 3;
                const float4* xr4 = (const float4*)(x_lds + s * INF);
                float acc = 0.f; FOR16(S1)
                inp_lds[s * HID + l] = acc;
            }
            BARRIER();
            {   // odd: inp(i+4), slot (i+4)&3
                const int s = (i + 4) & 3;
                const float4* xr4 = (const float4*)(x_lds + s * INF);
                float acc = 0.f; FOR16(S1)
                inp_lds[s * HID + l] = acc;
            }
            BARRIER();
        }
        #undef S1
    } else if (tid < 448) {
        // ============ R: rec scan + LIF, 2 neurons/lane ============
        const int l  = tid - 384;
        const int h0 = 2 * l, h1 = 2 * l + 1;

        const double vth0  = (double)v_th[h0],    vth1  = (double)v_th[h1];
        const double vleak = (double)v_leak1[0];
        const double vrs0  = (double)v_reset[h0], vrs1  = (double)v_reset[h1];
        const double dtm0  = 0.001 * (double)tau_mem[h0];
        const double dtm1  = 0.001 * (double)tau_mem[h1];
        const double dts0  = 0.001 * (double)tau_syn[h0];
        const double dts1  = 0.001 * (double)tau_syn[h1];

        double v0 = 0.0, v1 = 0.0, c0 = 0.0, c1 = 0.0;
        int cnt0 = 0, cnt1 = 0;
        unsigned long long me = 0ull, mo = 0ull;   // z(i-1): even/odd neurons

        __syncthreads();                       // B0
        BARRIER(); BARRIER(); BARRIER();       // B1,B2,B3

        for (int i = 0; i < T_STEPS; ++i) {
            float2 pp = *(const float2*)(pre_lds + (i & 1) * HID + h0);  // pre(i)

            double s00 = 0.0, s01 = 0.0, s10 = 0.0, s11 = 0.0;
            {
                unsigned long long A = me, Bm = mo;
                while (A | Bm) {
                    float2 w0 = make_float2(0.f, 0.f), w1 = w0, w2 = w0, w3 = w0,
                           w4 = w0, w5 = w0, w6 = w0, w7 = w0;
                    if (A)  { int j = __builtin_ctzll(A);  A  &= A - 1;  w0 = *(const float2*)(Wrec_T + (2 * j) * HID + h0); }
                    if (A)  { int j = __builtin_ctzll(A);  A  &= A - 1;  w1 = *(const float2*)(Wrec_T + (2 * j) * HID + h0); }
                    if (A)  { int j = __builtin_ctzll(A);  A  &= A - 1;  w2 = *(const float2*)(Wrec_T + (2 * j) * HID + h0); }
                    if (A)  { int j = __builtin_ctzll(A);  A  &= A - 1;  w3 = *(const float2*)(Wrec_T + (2 * j) * HID + h0); }
                    if (Bm) { int j = __builtin_ctzll(Bm); Bm &= Bm - 1; w4 = *(const float2*)(Wrec_T + (2 * j + 1) * HID + h0); }
                    if (Bm) { int j = __builtin_ctzll(Bm); Bm &= Bm - 1; w5 = *(const float2*)(Wrec_T + (2 * j + 1) * HID + h0); }
                    if (Bm) { int j = __builtin_ctzll(Bm); Bm &= Bm - 1; w6 = *(const float2*)(Wrec_T + (2 * j + 1) * HID + h0); }
                    if (Bm) { int j = __builtin_ctzll(Bm); Bm &= Bm - 1; w7 = *(const float2*)(Wrec_T + (2 * j + 1) * HID + h0); }
                    s00 += (double)w0.x; s10 += (double)w0.y;
                    s01 += (double)w1.x; s11 += (double)w1.y;
                    s00 += (double)w2.x; s10 += (double)w2.y;
                    s01 += (double)w3.x; s11 += (double)w3.y;
                    s00 += (double)w4.x; s10 += (double)w4.y;
                    s01 += (double)w5.x; s11 += (double)w5.y;
                    s00 += (double)w6.x; s10 += (double)w6.y;
                    s01 += (double)w7.x; s11 += (double)w7.y;
                }
            }
            double rec0 = s00 + s01;
            double rec1 = s10 + s11;

            double vd0 = v0 + dtm0 * ((vleak - v0) + c0);
            double id0 = c0 - dts0 * c0;
            bool   z0  = (vd0 - vth0) > 0.0;
            v0 = z0 ? vrs0 : vd0;
            c0 = (id0 + (double)pp.x) + rec0;
            cnt0 += z0 ? 1 : 0;

            double vd1 = v1 + dtm1 * ((vleak - v1) + c1);
            double id1 = c1 - dts1 * c1;
            bool   z1  = (vd1 - vth1) > 0.0;
            v1 = z1 ? vrs1 : vd1;
            c1 = (id1 + (double)pp.y) + rec1;
            cnt1 += z1 ? 1 : 0;

            me = __ballot(z0);
            mo = __ballot(z1);
            BARRIER();
        }

        pre_lds[h0] = (float)cnt0;   // park counts (counts <= 1024: exact)
        pre_lds[h1] = (float)cnt1;
    } else {
        // ============ X: x prefetch wave ============
        const int l = tid - 448;
        // stage x(0..3) -> slots 0..3; preload x(4),x(5),x(6)
        float t0 = x[(size_t)(0 * BATCH + b) * INF + l];
        float t1 = x[(size_t)(1 * BATCH + b) * INF + l];
        float t2 = x[(size_t)(2 * BATCH + b) * INF + l];
        float t3 = x[(size_t)(3 * BATCH + b) * INF + l];
        x_lds[0 * INF + l] = t0;
        x_lds[1 * INF + l] = t1;
        x_lds[2 * INF + l] = t2;
        x_lds[3 * INF + l] = t3;
        float rC = x[(size_t)(4 * BATCH + b) * INF + l];
        float rA = x[(size_t)(5 * BATCH + b) * INF + l];
        float rB = x[(size_t)(6 * BATCH + b) * INF + l];

        __syncthreads();                       // B0
        BARRIER();                             // B1
        BARRIER();                             // B2
        x_lds[0 * INF + l] = rC;               // P3: x(4) -> slot 0
        BARRIER();                             // B3
        for (int i = 0; i < T_STEPS; i += 2) {
            {   // even: write x(i+5), load x(i+7)
                x_lds[((i + 5) & 3) * INF + l] = rA;
                int tn = (i + 7 < T_STEPS) ? i + 7 : T_STEPS - 1;
                rA = x[((size_t)tn * BATCH + b) * INF + l];
            }
            BARRIER();
            {   // odd: write x(i+6), load x(i+8)
                x_lds[((i + 6) & 3) * INF + l] = rB;
                int tn = (i + 8 < T_STEPS) ? i + 8 : T_STEPS - 1;
                rB = x[((size_t)tn * BATCH + b) * INF + l];
            }
            BARRIER();
        }
    }

    __syncthreads();

    // ---- epilogue: z_sum[b] = (sum_t z)@W_out.T + T*b_out ; global spike count
    const float* cnt_lds = pre_lds;
    if (tid < OUTF) {
        double sAcc = 0.0;
        for (int hh = 0; hh < HID; ++hh)
            sAcc += (double)cnt_lds[hh] * (double)W_out[tid * HID + hh];
        out[(size_t)b * OUTF + tid] = (float)(sAcc + 1024.0 * (double)b_out[tid]);
    }
    if (tid == 0) {
        unsigned int tot = 0;
        for (int k2 = 0; k2 < HID; ++k2) tot += (unsigned int)cnt_lds[k2];
        atomicAdd(counter, tot);
    }
}

__global__ void finalize_kernel(float* __restrict__ out)
{
    unsigned int c = ((const unsigned int*)out)[BATCH * OUTF];
    out[BATCH * OUTF] = (float)c * 0x1p-26f;   // / (1024*512*128), exact pow2
}

extern "C" void kernel_launch(void* const* d_in, const int* in_sizes, int n_in,
                              void* d_out, int out_size, void* d_ws, size_t ws_size,
                              hipStream_t stream) {
    (void)in_sizes; (void)n_in; (void)d_ws; (void)ws_size; (void)out_size;

    const float* x       = (const float*)d_in[0];
    const float* W_in    = (const float*)d_in[1];
    const float* cWi     = (const float*)d_in[2];
    const float* cWr     = (const float*)d_in[3];
    const float* W_out   = (const float*)d_in[4];
    const float* b_out   = (const float*)d_in[5];
    // d_in[6] = alpha (unused in forward)
    const float* v_th    = (const float*)d_in[7];
    const float* v_leak  = (const float*)d_in[8];
    const float* v_reset = (const float*)d_in[9];
    const float* tau_mem = (const float*)d_in[10];
    const float* tau_syn = (const float*)d_in[11];
    float* out = (float*)d_out;
    unsigned int* counter = (unsigned int*)out + BATCH * OUTF;

    zero_kernel<<<1, 1, 0, stream>>>(counter);

    const size_t lds_bytes =
        (size_t)(HID * HID + 4 * HID + 4 * INF + 2 * HID + 2 * HID) * sizeof(float);
    snn_seq<<<dim3(512), dim3(512), lds_bytes, stream>>>(
        x, W_in, cWi, cWr, W_out, b_out, v_th, v_leak, v_reset,
        tau_mem, tau_syn, out, counter);

    finalize_kernel<<<1, 1, 0, stream>>>(out);
}